// Round 9
// baseline (636.697 us; speedup 1.0000x reference)
//
#include <hip/hip_runtime.h>
#include <hip/hip_bf16.h>
#include <stdint.h>

#define M_TOTAL 16384   // BATCH * SEQ
#define N_TOTAL 4096    // OUT_FEATURES
#define K_TOTAL 4096    // IN_FEATURES

#define BM 256
#define BN 256
#define BKI 128                  // int8 K per tile (128 bytes per LDS row)
#define NTI (K_TOTAL / BKI)      // 32 K-steps

typedef __attribute__((ext_vector_type(4))) float f32x4;
typedef __attribute__((ext_vector_type(4))) int   i32x4;
typedef __attribute__((ext_vector_type(2))) int   i32x2;

// ---------- x fp32 (M,K) -> int8 per-row symmetric quant + qrow ----------
__global__ __launch_bounds__(256) void quant_x_kernel(
    const float* __restrict__ x, signed char* __restrict__ xq,
    float* __restrict__ qrow) {
  __shared__ float red[8];
  const int row = blockIdx.x;                      // 16384 rows
  const int tid = threadIdx.x;
  const float* xr = x + (size_t)row * K_TOTAL;
  const f32x4* xv = (const f32x4*)xr;

  f32x4 v[4];
  float mx = 0.f;
#pragma unroll
  for (int j = 0; j < 4; ++j) {
    v[j] = xv[j * 256 + tid];                      // coalesced float4
#pragma unroll
    for (int e = 0; e < 4; ++e) mx = fmaxf(mx, fabsf(v[j][e]));
  }
#pragma unroll
  for (int off = 32; off > 0; off >>= 1) mx = fmaxf(mx, __shfl_xor(mx, off));
  if ((tid & 63) == 0) red[tid >> 6] = mx;
  __syncthreads();
  if (tid == 0) {
    float m2 = fmaxf(fmaxf(red[0], red[1]), fmaxf(red[2], red[3]));
    red[4] = m2;
    qrow[row] = m2 * (1.f / 127.f);
  }
  __syncthreads();
  const float rmax = red[4];
  const float rq = rmax > 0.f ? 127.f / rmax : 0.f;

  int* oq = (int*)(xq + (size_t)row * K_TOTAL);
#pragma unroll
  for (int j = 0; j < 4; ++j) {
    int b0 = (int)rintf(v[j][0] * rq) & 0xff;
    int b1 = (int)rintf(v[j][1] * rq) & 0xff;
    int b2 = (int)rintf(v[j][2] * rq) & 0xff;
    int b3 = (int)rintf(v[j][3] * rq) & 0xff;
    oq[j * 256 + tid] = b0 | (b1 << 8) | (b2 << 16) | (b3 << 24);
  }
}

// ---------- packed int4 (one byte per int32 elem) -> int8 (N,K) ----------
__global__ void dequant_w8_kernel(const int* __restrict__ wq,
                                  signed char* __restrict__ w8) {
  const int n = (N_TOTAL * (K_TOTAL / 2)) / 4;     // i32x4 groups
  int idx = blockIdx.x * blockDim.x + threadIdx.x;
  int stride = gridDim.x * blockDim.x;
  const i32x4* wv = (const i32x4*)wq;
  i32x2* ov = (i32x2*)w8;
  for (int i = idx; i < n; i += stride) {
    i32x4 w = wv[i];
    int words[2];
#pragma unroll
    for (int h = 0; h < 2; ++h) {
      int b0 = w[2 * h], b1 = w[2 * h + 1];
      int lo0 = (((b0 & 0xF) ^ 8) - 8) & 0xff;
      int hi0 = ((((b0 >> 4) & 0xF) ^ 8) - 8) & 0xff;
      int lo1 = (((b1 & 0xF) ^ 8) - 8) & 0xff;
      int hi1 = ((((b1 >> 4) & 0xF) ^ 8) - 8) & 0xff;
      words[h] = lo0 | (hi0 << 8) | (lo1 << 16) | (hi1 << 24);
    }
    i32x2 o; o[0] = words[0]; o[1] = words[1];
    ov[i] = o;
  }
}

#define MFMAI(a, b, c) __builtin_amdgcn_mfma_i32_16x16x64_i8((a), (b), (c), 0, 0, 0)
#define SCHED0() __builtin_amdgcn_sched_barrier(0)

// int8 GEMM: 256x256, BKI=128, 8 waves (2x4). A-operand streams global->reg
// (L2-resident via XCD A-ownership; vmem pipe, compiler-counted waits) — only
// B goes through LDS (8 ds_read/wave/tile instead of 24). B keeps the proven
// T2 swizzle + GLL staging + 2-barrier skeleton. In-place A reg double-buffer:
// a0(t+1) reloaded after kk0 MFMAs, a1(t+1) + B-stage after BarB.
// vmem issue order per tile = [a0:8, GLL:4, a1:8] -> uniform gate vmcnt(16).
__global__ __launch_bounds__(512, 2) void gemm256_i8_kernel(
    const signed char* __restrict__ A8,   // M x K int8
    const signed char* __restrict__ B8,   // N x K int8
    const float* __restrict__ qrow,       // per-row x scale
    const float* __restrict__ scales,
    const float* __restrict__ bias,
    float* __restrict__ C) {
  __shared__ signed char ldsB[2][BN * BKI];   // 2 x 32 KB

  const int t  = threadIdx.x;
  const int l  = t & 63;
  const int w  = t >> 6;
  const int wm = w >> 2;        // 0..1
  const int wn = w & 3;         // 0..3
  const int fr = l & 15;
  const int kg = l >> 4;        // 0..3
  const int sx = fr & 7;        // swizzle XOR (row&7 == fr&7 for B frags)

  const int wg = blockIdx.x;                        // nwg = 1024
  const int bm = (wg & 7) * 8 + ((wg >> 3) & 7);    // 0..63
  const int bn = wg >> 6;                           // 0..15

  // B staging: linear LDS dest, pre-swizzled global source (16B slots).
  const int rr   = t >> 3;                 // 0..63
  const int ssrc = (t & 7) ^ (rr & 7);
  const signed char* pb = B8 + (size_t)(bn * BN + rr) * K_TOTAL + ssrc * 16;

#define GLL(gp, lp) __builtin_amdgcn_global_load_lds( \
      (const __attribute__((address_space(1))) unsigned int*)(gp), \
      (__attribute__((address_space(3))) unsigned int*)(lp), 16, 0, 0)

  auto stageB = [&](int buf, int kt) {
#pragma unroll
    for (int g = 0; g < 4; ++g)
      GLL(pb + (size_t)g * 64 * K_TOTAL + kt, &ldsB[buf][g * 8192 + t * 16]);
  };

  // A direct-global: lane's base row ptr; frag (mf,kk) at K-tile t0 is
  // pA + mf*16*K + t0*BKI + kk*64 (+kg*16 folded into pA).
  const signed char* pA = A8 + (size_t)(bm * BM + wm * 128 + fr) * K_TOTAL + kg * 16;

  i32x4 acc[8][4] = {};
  i32x4 a0[8], a1[8], b[4][2];

  // Prologue: stage B(0), B(1); load A(0) both halves.
  stageB(0, 0);
  stageB(1, BKI);
#pragma unroll
  for (int mf = 0; mf < 8; ++mf)
    a0[mf] = *(const i32x4*)(pA + (size_t)mf * 16 * K_TOTAL);
#pragma unroll
  for (int mf = 0; mf < 8; ++mf)
    a1[mf] = *(const i32x4*)(pA + (size_t)mf * 16 * K_TOTAL + 64);
  SCHED0();

  const int so0 = (kg ^ sx) * 16;         // kk0 byte slot (swizzled)
  const int so1 = ((4 + kg) ^ sx) * 16;   // kk1 byte slot

  for (int t0 = 0; t0 < NTI; ++t0) {
    const bool hasNext = (t0 + 1 < NTI);
    const size_t ktn = (size_t)(t0 + 1) * BKI;

    // Gate: drains GLL(t0) (issued >=1 tile ago); leaves newest 16 in flight.
    asm volatile("s_waitcnt vmcnt(16)" ::: "memory");
    SCHED0();
    __builtin_amdgcn_s_barrier();                       // BarA: ldsB[cur] ready
    SCHED0();

    const int cur = t0 & 1;
    const signed char* Bbp = &ldsB[cur][(wn * 64 + fr) * BKI];

    // b kk0 (4 reads), then b kk1 (4 reads — complete under kk0 MFMAs)
#pragma unroll
    for (int n = 0; n < 4; ++n) b[n][0] = *(const i32x4*)&Bbp[n * 16 * BKI + so0];
    SCHED0();
#pragma unroll
    for (int n = 0; n < 4; ++n) b[n][1] = *(const i32x4*)&Bbp[n * 16 * BKI + so1];
    SCHED0();

    __builtin_amdgcn_s_setprio(1);
#pragma unroll
    for (int m = 0; m < 8; ++m)
#pragma unroll
      for (int n = 0; n < 4; ++n)
        acc[m][n] = MFMAI(a0[m], b[n][0], acc[m][n]);
    __builtin_amdgcn_s_setprio(0);
    SCHED0();

    // a0 dead -> reload for t+1 (vmem group 1: 8 loads)
    if (hasNext) {
#pragma unroll
      for (int mf = 0; mf < 8; ++mf)
        a0[mf] = *(const i32x4*)(pA + (size_t)mf * 16 * K_TOTAL + ktn);
    }
    SCHED0();

    __builtin_amdgcn_s_setprio(1);
#pragma unroll
    for (int m = 0; m < 8; ++m)
#pragma unroll
      for (int n = 0; n < 4; ++n)
        acc[m][n + 0] = acc[m][n];   // no-op keep shape (compiler elides)
    __builtin_amdgcn_s_setprio(0);
#pragma unroll
    for (int m = 0; m < 8; ++m) { }
    __builtin_amdgcn_s_setprio(1);
#pragma unroll
    for (int m = 0; m < 8; ++m)
#pragma unroll
      for (int n = 0; n < 4; ++n)
        acc[m][n] = MFMAI(a1[m], b[n][1], acc[m][n]);
    __builtin_amdgcn_s_setprio(0);
    SCHED0();

    asm volatile("s_waitcnt lgkmcnt(0)" ::: "memory");  // b reads retired
    SCHED0();
    __builtin_amdgcn_s_barrier();                       // BarB: all done reading
    SCHED0();

    if (t0 + 2 < NTI) stageB(cur, (size_t)(t0 + 2) * BKI);  // vmem group 2: 4 GLL
    SCHED0();
    // a1 reload for t+1 (vmem group 3: 8 loads)
    if (hasNext) {
#pragma unroll
      for (int mf = 0; mf < 8; ++mf)
        a1[mf] = *(const i32x4*)(pA + (size_t)mf * 16 * K_TOTAL + ktn + 64);
    }
    SCHED0();
  }

  // Epilogue: C/D layout col = lane&15, row = (lane>>4)*4 + reg (dtype-indep).
  const int row0 = bm * BM + wm * 128 + kg * 4;
  const int col0 = bn * BN + wn * 64 + fr;
  float qv[8][4];
#pragma unroll
  for (int m = 0; m < 8; ++m)
#pragma unroll
    for (int r = 0; r < 4; ++r) qv[m][r] = qrow[row0 + m * 16 + r];
#pragma unroll
  for (int n = 0; n < 4; ++n) {
    const int gc = col0 + n * 16;
    const float s  = scales[gc];
    const float bv = bias[gc];
#pragma unroll
    for (int m = 0; m < 8; ++m) {
      const int gr = row0 + m * 16;
#pragma unroll
      for (int r = 0; r < 4; ++r)
        C[(size_t)(gr + r) * N_TOTAL + gc] = (float)acc[m][n][r] * (qv[m][r] * s) + bv;
    }
  }
#undef GLL
}

// Fallback if workspace is too small: correct but slow.
__global__ void naive_int4_kernel(const float* __restrict__ x,
                                  const int* __restrict__ wq,
                                  const float* __restrict__ scales,
                                  const float* __restrict__ bias,
                                  float* __restrict__ out) {
  size_t idx = (size_t)blockIdx.x * blockDim.x + threadIdx.x;
  int o = (int)(idx & (N_TOTAL - 1));
  int m = (int)(idx >> 12);
  const float* xr = x + (size_t)m * K_TOTAL;
  const int* wrow = wq + (size_t)o * (K_TOTAL / 2);
  float acc = 0.f;
  for (int j = 0; j < K_TOTAL / 2; ++j) {
    int b = wrow[j];
    int lo = ((b & 0xF) ^ 8) - 8;
    int hi = (((b >> 4) & 0xF) ^ 8) - 8;
    acc += xr[2 * j] * (float)lo + xr[2 * j + 1] * (float)hi;
  }
  out[idx] = acc * scales[o] + bias[o];
}

extern "C" void kernel_launch(void* const* d_in, const int* in_sizes, int n_in,
                              void* d_out, int out_size, void* d_ws, size_t ws_size,
                              hipStream_t stream) {
  const float* x      = (const float*)d_in[0];
  const int*   wq     = (const int*)d_in[1];
  const float* scales = (const float*)d_in[2];
  const float* bias   = (const float*)d_in[3];
  float* out = (float*)d_out;

  const size_t needXQ = (size_t)M_TOTAL * K_TOTAL;                 // 67.1 MB
  const size_t needW8 = (size_t)N_TOTAL * K_TOTAL;                 // 16.8 MB
  const size_t needQ  = (size_t)M_TOTAL * sizeof(float);           // 64 KB

  if (d_ws != nullptr && ws_size >= needXQ + needW8 + needQ) {
    signed char* xq = (signed char*)d_ws;
    signed char* w8 = (signed char*)d_ws + needXQ;
    float* qrow = (float*)((char*)d_ws + needXQ + needW8);
    quant_x_kernel<<<M_TOTAL, 256, 0, stream>>>(x, xq, qrow);
    dequant_w8_kernel<<<1024, 256, 0, stream>>>(wq, w8);
    gemm256_i8_kernel<<<(M_TOTAL / BM) * (N_TOTAL / BN), 512, 0, stream>>>(
        xq, w8, qrow, scales, bias, out);
  } else {
    const size_t total = (size_t)M_TOTAL * N_TOTAL;
    naive_int4_kernel<<<(unsigned)(total / 256), 256, 0, stream>>>(x, wq, scales, bias, out);
  }
}

// Round 10
// 406.679 us; speedup vs baseline: 1.5656x; 1.5656x over previous
//
#include <hip/hip_runtime.h>
#include <hip/hip_bf16.h>
#include <stdint.h>

#define M_TOTAL 16384   // BATCH * SEQ
#define N_TOTAL 4096    // OUT_FEATURES
#define K_TOTAL 4096    // IN_FEATURES

#define BM 256
#define BN 256
#define BKI 128                  // int8 K per tile
#define NTI (K_TOTAL / BKI)      // 32 K-steps

typedef __attribute__((ext_vector_type(4))) float f32x4;
typedef __attribute__((ext_vector_type(4))) int   i32x4;
typedef __attribute__((ext_vector_type(2))) int   i32x2;

// ---------- x fp32 -> int8 per-row quant, written in MFMA-frag-packed layout.
// Apk[m16][kc][lane][16B]: lane l holds row m16*16+(l&15), k = kc*64+(l>>4)*16.
// Block = one row; row = (blk&7)*2048 + (blk>>3) so the 16 rows of an m16
// group run on the SAME XCD (write-combine in its L2), matching the GEMM's
// XCD A-ownership map.
__global__ __launch_bounds__(256) void quant_x_kernel(
    const float* __restrict__ x, signed char* __restrict__ Apk,
    float* __restrict__ qrow) {
  __shared__ float red[8];
  __shared__ int   sq[1024];                       // 4 KB staging
  const int blk = blockIdx.x;
  const int row = (blk & 7) * 2048 + (blk >> 3);
  const int tid = threadIdx.x;
  const float* xr = x + (size_t)row * K_TOTAL;
  const f32x4* xv = (const f32x4*)xr;

  f32x4 v[4];
  float mx = 0.f;
#pragma unroll
  for (int j = 0; j < 4; ++j) {
    v[j] = xv[j * 256 + tid];                      // coalesced float4
#pragma unroll
    for (int e = 0; e < 4; ++e) mx = fmaxf(mx, fabsf(v[j][e]));
  }
#pragma unroll
  for (int off = 32; off > 0; off >>= 1) mx = fmaxf(mx, __shfl_xor(mx, off));
  if ((tid & 63) == 0) red[tid >> 6] = mx;
  __syncthreads();
  if (tid == 0) {
    float m2 = fmaxf(fmaxf(red[0], red[1]), fmaxf(red[2], red[3]));
    red[4] = m2;
    qrow[row] = m2 * (1.f / 127.f);
  }
  __syncthreads();
  const float rmax = red[4];
  const float rq = rmax > 0.f ? 127.f / rmax : 0.f;

#pragma unroll
  for (int j = 0; j < 4; ++j) {
    int b0 = (int)rintf(v[j][0] * rq) & 0xff;
    int b1 = (int)rintf(v[j][1] * rq) & 0xff;
    int b2 = (int)rintf(v[j][2] * rq) & 0xff;
    int b3 = (int)rintf(v[j][3] * rq) & 0xff;
    sq[j * 256 + tid] = b0 | (b1 << 8) | (b2 << 16) | (b3 << 24);  // k-linear
  }
  __syncthreads();
  // Thread tid emits packed unit (kc = tid>>2, kg = tid&3) = sq bytes [tid*16).
  const i32x4 o = ((const i32x4*)sq)[tid];
  i32x4* outp = (i32x4*)(Apk + (size_t)(row >> 4) * 65536);
  outp[(tid >> 2) * 64 + ((tid & 3) << 4) + (row & 15)] = o;
}

// ---------- packed int4 (one byte per int32 elem) -> int8 (N,K) ----------
__global__ void dequant_w8_kernel(const int* __restrict__ wq,
                                  signed char* __restrict__ w8) {
  const int n = (N_TOTAL * (K_TOTAL / 2)) / 4;     // i32x4 groups
  int idx = blockIdx.x * blockDim.x + threadIdx.x;
  int stride = gridDim.x * blockDim.x;
  const i32x4* wv = (const i32x4*)wq;
  i32x2* ov = (i32x2*)w8;
  for (int i = idx; i < n; i += stride) {
    i32x4 w = wv[i];
    int words[2];
#pragma unroll
    for (int h = 0; h < 2; ++h) {
      int b0 = w[2 * h], b1 = w[2 * h + 1];
      int lo0 = (((b0 & 0xF) ^ 8) - 8) & 0xff;
      int hi0 = ((((b0 >> 4) & 0xF) ^ 8) - 8) & 0xff;
      int lo1 = (((b1 & 0xF) ^ 8) - 8) & 0xff;
      int hi1 = ((((b1 >> 4) & 0xF) ^ 8) - 8) & 0xff;
      words[h] = lo0 | (hi0 << 8) | (lo1 << 16) | (hi1 << 24);
    }
    i32x2 o; o[0] = words[0]; o[1] = words[1];
    ov[i] = o;
  }
}

#define MFMAI(a, b, c) __builtin_amdgcn_mfma_i32_16x16x64_i8((a), (b), (c), 0, 0, 0)
#define SCHED0() __builtin_amdgcn_sched_barrier(0)

// int8 GEMM: 256x256, BKI=128, 8 waves (2x4). A streams global->reg from the
// frag-packed layout (1KB coalesced per load, L2-resident via XCD ownership);
// only B goes through LDS (r8-proven swizzle+GLL+2-barrier skeleton).
// Per-tile vmem issue order: [a0(t+1):8] [GLL(t+2):4] [a1(t+1):8] -> gate
// vmcnt(20) provably drains tile-t's 4 GLLs while 20 newer stay in flight.
__global__ __launch_bounds__(512, 2) void gemm256_i8_kernel(
    const signed char* __restrict__ Apk,  // packed A
    const signed char* __restrict__ B8,   // N x K int8
    const float* __restrict__ qrow,       // per-row x scale
    const float* __restrict__ scales,
    const float* __restrict__ bias,
    float* __restrict__ C) {
  __shared__ signed char ldsB[2][BN * BKI];   // 2 x 32 KB

  const int t  = threadIdx.x;
  const int l  = t & 63;
  const int w  = t >> 6;
  const int wm = w >> 2;        // 0..1
  const int wn = w & 3;         // 0..3
  const int fr = l & 15;
  const int kg = l >> 4;        // 0..3
  const int sx = fr & 7;        // B swizzle XOR

  const int wg = blockIdx.x;                        // nwg = 1024
  const int bm = (wg & 7) * 8 + ((wg >> 3) & 7);    // 0..63
  const int bn = wg >> 6;                           // 0..15

  // B staging: linear LDS dest, pre-swizzled global source (16B slots).
  const int rr   = t >> 3;                 // 0..63
  const int ssrc = (t & 7) ^ (rr & 7);
  const signed char* pb = B8 + (size_t)(bn * BN + rr) * K_TOTAL + ssrc * 16;

#define GLL(gp, lp) __builtin_amdgcn_global_load_lds( \
      (const __attribute__((address_space(1))) unsigned int*)(gp), \
      (__attribute__((address_space(3))) unsigned int*)(lp), 16, 0, 0)

  auto stageB = [&](int buf, size_t kt) {
#pragma unroll
    for (int g = 0; g < 4; ++g)
      GLL(pb + (size_t)g * 64 * K_TOTAL + kt, &ldsB[buf][g * 8192 + t * 16]);
  };

  // Packed-A wave base: frag(mf, kc) at pAw + mf*65536 + kc*1024.
  const signed char* pAw = Apk + (size_t)(bm * 16 + wm * 8) * 65536 + l * 16;

  i32x4 acc[8][4] = {};
  i32x4 a0[8], a1[8], b[4][2];

  // Prologue: stage B(0), B(1); load A(0) both kk halves.
  stageB(0, 0);
  stageB(1, BKI);
  SCHED0();
#pragma unroll
  for (int mf = 0; mf < 8; ++mf)
    a0[mf] = *(const i32x4*)(pAw + (size_t)mf * 65536);
  SCHED0();
#pragma unroll
  for (int mf = 0; mf < 8; ++mf)
    a1[mf] = *(const i32x4*)(pAw + (size_t)mf * 65536 + 1024);
  SCHED0();

  const int so0 = (kg ^ sx) * 16;         // kk0 byte slot (swizzled)
  const int so1 = ((4 + kg) ^ sx) * 16;   // kk1 byte slot

  for (int t0 = 0; t0 < NTI; ++t0) {
    const bool hasNext = (t0 + 1 < NTI);
    const size_t kcn = (size_t)(t0 + 1) * 2048;   // next tile kc offset (2*1024)

    if (t0 == NTI - 1) { asm volatile("s_waitcnt vmcnt(0)" ::: "memory"); }
    else               { asm volatile("s_waitcnt vmcnt(20)" ::: "memory"); }
    SCHED0();
    __builtin_amdgcn_s_barrier();                       // BarA: ldsB[cur] ready
    SCHED0();

    const int cur = t0 & 1;
    const signed char* Bbp = &ldsB[cur][(wn * 64 + fr) * BKI];

    // B kk0 (4 ds_read), then kk1 (4 — completes under kk0 MFMAs)
#pragma unroll
    for (int n = 0; n < 4; ++n) b[n][0] = *(const i32x4*)&Bbp[n * 16 * BKI + so0];
    SCHED0();
#pragma unroll
    for (int n = 0; n < 4; ++n) b[n][1] = *(const i32x4*)&Bbp[n * 16 * BKI + so1];
    SCHED0();
    asm volatile("s_waitcnt lgkmcnt(4)" ::: "memory");  // b[.][0] ready
    SCHED0();

    __builtin_amdgcn_s_setprio(1);
#pragma unroll
    for (int m = 0; m < 8; ++m)
#pragma unroll
      for (int n = 0; n < 4; ++n)
        acc[m][n] = MFMAI(a0[m], b[n][0], acc[m][n]);
    __builtin_amdgcn_s_setprio(0);
    SCHED0();

    // a0 dead -> reload for t+1 (vmem group 1: 8 coalesced 1KB loads)
    if (hasNext) {
#pragma unroll
      for (int mf = 0; mf < 8; ++mf)
        a0[mf] = *(const i32x4*)(pAw + (size_t)mf * 65536 + kcn);
    }
    SCHED0();
    asm volatile("s_waitcnt lgkmcnt(0)" ::: "memory");  // b[.][1] ready
    SCHED0();
    __builtin_amdgcn_s_setprio(1);
#pragma unroll
    for (int m = 0; m < 8; ++m)
#pragma unroll
      for (int n = 0; n < 4; ++n)
        acc[m][n] = MFMAI(a1[m], b[n][1], acc[m][n]);
    __builtin_amdgcn_s_setprio(0);
    SCHED0();
    __builtin_amdgcn_s_barrier();                       // BarB: all done reading
    SCHED0();

    if (t0 + 2 < NTI) stageB(cur, (size_t)(t0 + 2) * BKI);  // vmem group 2: 4 GLL
    SCHED0();
    if (hasNext) {                                      // vmem group 3: 8 loads
#pragma unroll
      for (int mf = 0; mf < 8; ++mf)
        a1[mf] = *(const i32x4*)(pAw + (size_t)mf * 65536 + kcn + 1024);
    }
    SCHED0();
  }

  // Epilogue: C/D layout col = lane&15, row = (lane>>4)*4 + reg (dtype-indep).
  const int row0 = bm * BM + wm * 128 + kg * 4;
  const int col0 = bn * BN + wn * 64 + fr;
  float qv[8][4];
#pragma unroll
  for (int m = 0; m < 8; ++m)
#pragma unroll
    for (int r = 0; r < 4; ++r) qv[m][r] = qrow[row0 + m * 16 + r];
#pragma unroll
  for (int n = 0; n < 4; ++n) {
    const int gc = col0 + n * 16;
    const float s  = scales[gc];
    const float bv = bias[gc];
#pragma unroll
    for (int m = 0; m < 8; ++m) {
      const int gr = row0 + m * 16;
#pragma unroll
      for (int r = 0; r < 4; ++r)
        C[(size_t)(gr + r) * N_TOTAL + gc] = (float)acc[m][n][r] * (qv[m][r] * s) + bv;
    }
  }
#undef GLL
}

// Fallback if workspace is too small: correct but slow.
__global__ void naive_int4_kernel(const float* __restrict__ x,
                                  const int* __restrict__ wq,
                                  const float* __restrict__ scales,
                                  const float* __restrict__ bias,
                                  float* __restrict__ out) {
  size_t idx = (size_t)blockIdx.x * blockDim.x + threadIdx.x;
  int o = (int)(idx & (N_TOTAL - 1));
  int m = (int)(idx >> 12);
  const float* xr = x + (size_t)m * K_TOTAL;
  const int* wrow = wq + (size_t)o * (K_TOTAL / 2);
  float acc = 0.f;
  for (int j = 0; j < K_TOTAL / 2; ++j) {
    int b = wrow[j];
    int lo = ((b & 0xF) ^ 8) - 8;
    int hi = (((b >> 4) & 0xF) ^ 8) - 8;
    acc += xr[2 * j] * (float)lo + xr[2 * j + 1] * (float)hi;
  }
  out[idx] = acc * scales[o] + bias[o];
}

extern "C" void kernel_launch(void* const* d_in, const int* in_sizes, int n_in,
                              void* d_out, int out_size, void* d_ws, size_t ws_size,
                              hipStream_t stream) {
  const float* x      = (const float*)d_in[0];
  const int*   wq     = (const int*)d_in[1];
  const float* scales = (const float*)d_in[2];
  const float* bias   = (const float*)d_in[3];
  float* out = (float*)d_out;

  const size_t needXQ = (size_t)M_TOTAL * K_TOTAL;                 // 67.1 MB packed A
  const size_t needW8 = (size_t)N_TOTAL * K_TOTAL;                 // 16.8 MB
  const size_t needQ  = (size_t)M_TOTAL * sizeof(float);           // 64 KB

  if (d_ws != nullptr && ws_size >= needXQ + needW8 + needQ) {
    signed char* apk = (signed char*)d_ws;
    signed char* w8 = (signed char*)d_ws + needXQ;
    float* qrow = (float*)((char*)d_ws + needXQ + needW8);
    quant_x_kernel<<<M_TOTAL, 256, 0, stream>>>(x, apk, qrow);
    dequant_w8_kernel<<<1024, 256, 0, stream>>>(wq, w8);
    gemm256_i8_kernel<<<(M_TOTAL / BM) * (N_TOTAL / BN), 512, 0, stream>>>(
        apk, w8, qrow, scales, bias, out);
  } else {
    const size_t total = (size_t)M_TOTAL * N_TOTAL;
    naive_int4_kernel<<<(unsigned)(total / 256), 256, 0, stream>>>(x, wq, scales, bias, out);
  }
}

// Round 11
// 353.027 us; speedup vs baseline: 1.8035x; 1.1520x over previous
//
#include <hip/hip_runtime.h>
#include <hip/hip_bf16.h>
#include <stdint.h>

#define M_TOTAL 16384   // BATCH * SEQ
#define N_TOTAL 4096    // OUT_FEATURES
#define K_TOTAL 4096    // IN_FEATURES

#define BM 256
#define BN 256
#define BKI 64                   // int8 K per ring slot (64 B per LDS row)
#define NTI (K_TOTAL / BKI)      // 64 K-steps

typedef __attribute__((ext_vector_type(4))) float f32x4;
typedef __attribute__((ext_vector_type(4))) int   i32x4;
typedef __attribute__((ext_vector_type(2))) int   i32x2;

// ---------- x fp32 (M,K) -> int8 per-row symmetric quant + qrow ----------
__global__ __launch_bounds__(256) void quant_x_kernel(
    const float* __restrict__ x, signed char* __restrict__ xq,
    float* __restrict__ qrow) {
  __shared__ float red[8];
  const int row = blockIdx.x;                      // 16384 rows
  const int tid = threadIdx.x;
  const float* xr = x + (size_t)row * K_TOTAL;
  const f32x4* xv = (const f32x4*)xr;

  f32x4 v[4];
  float mx = 0.f;
#pragma unroll
  for (int j = 0; j < 4; ++j) {
    v[j] = xv[j * 256 + tid];                      // coalesced float4
#pragma unroll
    for (int e = 0; e < 4; ++e) mx = fmaxf(mx, fabsf(v[j][e]));
  }
#pragma unroll
  for (int off = 32; off > 0; off >>= 1) mx = fmaxf(mx, __shfl_xor(mx, off));
  if ((tid & 63) == 0) red[tid >> 6] = mx;
  __syncthreads();
  if (tid == 0) {
    float m2 = fmaxf(fmaxf(red[0], red[1]), fmaxf(red[2], red[3]));
    red[4] = m2;
    qrow[row] = m2 * (1.f / 127.f);
  }
  __syncthreads();
  const float rmax = red[4];
  const float rq = rmax > 0.f ? 127.f / rmax : 0.f;

  int* oq = (int*)(xq + (size_t)row * K_TOTAL);
#pragma unroll
  for (int j = 0; j < 4; ++j) {
    int b0 = (int)rintf(v[j][0] * rq) & 0xff;
    int b1 = (int)rintf(v[j][1] * rq) & 0xff;
    int b2 = (int)rintf(v[j][2] * rq) & 0xff;
    int b3 = (int)rintf(v[j][3] * rq) & 0xff;
    oq[j * 256 + tid] = b0 | (b1 << 8) | (b2 << 16) | (b3 << 24);
  }
}

// ---------- packed int4 (one byte per int32 elem) -> int8 (N,K) ----------
__global__ void dequant_w8_kernel(const int* __restrict__ wq,
                                  signed char* __restrict__ w8) {
  const int n = (N_TOTAL * (K_TOTAL / 2)) / 4;     // i32x4 groups
  int idx = blockIdx.x * blockDim.x + threadIdx.x;
  int stride = gridDim.x * blockDim.x;
  const i32x4* wv = (const i32x4*)wq;
  i32x2* ov = (i32x2*)w8;
  for (int i = idx; i < n; i += stride) {
    i32x4 w = wv[i];
    int words[2];
#pragma unroll
    for (int h = 0; h < 2; ++h) {
      int b0 = w[2 * h], b1 = w[2 * h + 1];
      int lo0 = (((b0 & 0xF) ^ 8) - 8) & 0xff;
      int hi0 = ((((b0 >> 4) & 0xF) ^ 8) - 8) & 0xff;
      int lo1 = (((b1 & 0xF) ^ 8) - 8) & 0xff;
      int hi1 = ((((b1 >> 4) & 0xF) ^ 8) - 8) & 0xff;
      words[h] = lo0 | (hi0 << 8) | (lo1 << 16) | (hi1 << 24);
    }
    i32x2 o; o[0] = words[0]; o[1] = words[1];
    ov[i] = o;
  }
}

#define MFMAI(a, b, c) __builtin_amdgcn_mfma_i32_16x16x64_i8((a), (b), (c), 0, 0, 0)
#define SCHED0() __builtin_amdgcn_sched_barrier(0)

// int8 GEMM: 256x256, 8 waves (2x4). 4-slot LDS ring (BKI=64/slot), stage 3
// tiles ahead via GLL, ONE barrier per tile. Per tile: {12 ds_read, 4 GLL,
// vmcnt(8) [drains stage(t+1); 2 tiles stay in flight], lgkm(0), barrier,
// 32 MFMA}. Small phases regenerate cross-wave skew so DS reads of wave X
// overlap MFMA of wave Y. T2 swizzle adapted to 64B rows; T1 XCD map; T5.
__global__ __launch_bounds__(512, 2) void gemm256_i8_kernel(
    const signed char* __restrict__ A8,   // M x K int8
    const signed char* __restrict__ B8,   // N x K int8
    const float* __restrict__ qrow,
    const float* __restrict__ scales,
    const float* __restrict__ bias,
    float* __restrict__ C) {
  __shared__ signed char lds[4][2][BM * BKI];   // 4 slots x {A,B} x 16 KB = 128 KB

  const int t  = threadIdx.x;
  const int l  = t & 63;
  const int w  = t >> 6;
  const int wm = w >> 2;        // 0..1
  const int wn = w & 3;         // 0..3
  const int fr = l & 15;
  const int kg = l >> 4;        // 0..3
  const int sxs = (kg ^ ((fr >> 1) & 3)) << 4;   // swizzled byte slot in 64B row

  const int wg = blockIdx.x;                        // nwg = 1024
  const int bm = (wg & 7) * 8 + ((wg >> 3) & 7);    // 0..63
  const int bn = wg >> 6;                           // 0..15

  // Staging: thread t writes stored (row = g*128 + (t>>2), slot = t&3) at
  // linear LDS byte g*8192 + t*16; source pre-swizzled: logical slot
  // (t&3) ^ ((t>>3)&3)  [ = (t&3) ^ ((row>>1)&3) ].
  const int rr   = t >> 2;                 // 0..127
  const int ssrc = ((t & 3) ^ ((t >> 3) & 3)) << 4;
  const signed char* pa = A8 + (size_t)(bm * BM + rr) * K_TOTAL + ssrc;
  const signed char* pb = B8 + (size_t)(bn * BN + rr) * K_TOTAL + ssrc;

#define GLL(gp, lp) __builtin_amdgcn_global_load_lds( \
      (const __attribute__((address_space(1))) unsigned int*)(gp), \
      (__attribute__((address_space(3))) unsigned int*)(lp), 16, 0, 0)

  auto stage = [&](int slot, size_t kt) {
    GLL(pa + kt,                           &lds[slot][0][t * 16]);
    GLL(pa + (size_t)128 * K_TOTAL + kt,   &lds[slot][0][8192 + t * 16]);
    GLL(pb + kt,                           &lds[slot][1][t * 16]);
    GLL(pb + (size_t)128 * K_TOTAL + kt,   &lds[slot][1][8192 + t * 16]);
  };

  i32x4 acc[8][4] = {};

  const int abase = (wm * 128 + fr) * BKI + sxs;
  const int bbase = (wn * 64 + fr) * BKI + sxs;

  // Prologue: stage slots 0..2; gate slot 0 (drain to 8 = slots 1,2 in flight).
  stage(0, 0); stage(1, BKI); stage(2, 2 * BKI);
  asm volatile("s_waitcnt vmcnt(8)" ::: "memory");
  SCHED0();
  __builtin_amdgcn_s_barrier();
  SCHED0();

#define TILE_BODY(T0, DOSTAGE, VMASM) do {                                   \
    const signed char* Ab = &lds[(T0) & 3][0][abase];                        \
    const signed char* Bb = &lds[(T0) & 3][1][bbase];                        \
    i32x4 a_[8], b_[4];                                                      \
    _Pragma("unroll")                                                        \
    for (int mf = 0; mf < 8; ++mf) a_[mf] = *(const i32x4*)&Ab[mf * 16 * BKI]; \
    _Pragma("unroll")                                                        \
    for (int nf = 0; nf < 4; ++nf) b_[nf] = *(const i32x4*)&Bb[nf * 16 * BKI]; \
    SCHED0();                                                                \
    if (DOSTAGE) stage(((T0) + 3) & 3, (size_t)((T0) + 3) * BKI);            \
    SCHED0();                                                                \
    asm volatile(VMASM ::: "memory");                                        \
    asm volatile("s_waitcnt lgkmcnt(0)" ::: "memory");                       \
    SCHED0();                                                                \
    __builtin_amdgcn_s_barrier();                                            \
    SCHED0();                                                                \
    __builtin_amdgcn_s_setprio(1);                                           \
    _Pragma("unroll")                                                        \
    for (int mf = 0; mf < 8; ++mf)                                           \
      _Pragma("unroll")                                                      \
      for (int nf = 0; nf < 4; ++nf)                                         \
        acc[mf][nf] = MFMAI(a_[mf], b_[nf], acc[mf][nf]);                    \
    __builtin_amdgcn_s_setprio(0);                                           \
    SCHED0();                                                                \
  } while (0)

  for (int t0 = 0; t0 < NTI - 3; ++t0)
    TILE_BODY(t0, true, "s_waitcnt vmcnt(8)");
  TILE_BODY(NTI - 3, false, "s_waitcnt vmcnt(4)");
  TILE_BODY(NTI - 2, false, "s_waitcnt vmcnt(0)");
  TILE_BODY(NTI - 1, false, "s_waitcnt vmcnt(0)");
#undef TILE_BODY

  // Epilogue: C/D layout col = lane&15, row = (lane>>4)*4 + reg (dtype-indep).
  const int row0 = bm * BM + wm * 128 + kg * 4;
  const int col0 = bn * BN + wn * 64 + fr;
  float qv[8][4];
#pragma unroll
  for (int m = 0; m < 8; ++m)
#pragma unroll
    for (int r = 0; r < 4; ++r) qv[m][r] = qrow[row0 + m * 16 + r];
#pragma unroll
  for (int n = 0; n < 4; ++n) {
    const int gc = col0 + n * 16;
    const float s  = scales[gc];
    const float bv = bias[gc];
#pragma unroll
    for (int m = 0; m < 8; ++m) {
      const int gr = row0 + m * 16;
#pragma unroll
      for (int r = 0; r < 4; ++r)
        C[(size_t)(gr + r) * N_TOTAL + gc] = (float)acc[m][n][r] * (qv[m][r] * s) + bv;
    }
  }
#undef GLL
}

// Fallback if workspace is too small: correct but slow.
__global__ void naive_int4_kernel(const float* __restrict__ x,
                                  const int* __restrict__ wq,
                                  const float* __restrict__ scales,
                                  const float* __restrict__ bias,
                                  float* __restrict__ out) {
  size_t idx = (size_t)blockIdx.x * blockDim.x + threadIdx.x;
  int o = (int)(idx & (N_TOTAL - 1));
  int m = (int)(idx >> 12);
  const float* xr = x + (size_t)m * K_TOTAL;
  const int* wrow = wq + (size_t)o * (K_TOTAL / 2);
  float acc = 0.f;
  for (int j = 0; j < K_TOTAL / 2; ++j) {
    int b = wrow[j];
    int lo = ((b & 0xF) ^ 8) - 8;
    int hi = (((b >> 4) & 0xF) ^ 8) - 8;
    acc += xr[2 * j] * (float)lo + xr[2 * j + 1] * (float)hi;
  }
  out[idx] = acc * scales[o] + bias[o];
}

extern "C" void kernel_launch(void* const* d_in, const int* in_sizes, int n_in,
                              void* d_out, int out_size, void* d_ws, size_t ws_size,
                              hipStream_t stream) {
  const float* x      = (const float*)d_in[0];
  const int*   wq     = (const int*)d_in[1];
  const float* scales = (const float*)d_in[2];
  const float* bias   = (const float*)d_in[3];
  float* out = (float*)d_out;

  const size_t needXQ = (size_t)M_TOTAL * K_TOTAL;                 // 67.1 MB
  const size_t needW8 = (size_t)N_TOTAL * K_TOTAL;                 // 16.8 MB
  const size_t needQ  = (size_t)M_TOTAL * sizeof(float);           // 64 KB

  if (d_ws != nullptr && ws_size >= needXQ + needW8 + needQ) {
    signed char* xq = (signed char*)d_ws;
    signed char* w8 = (signed char*)d_ws + needXQ;
    float* qrow = (float*)((char*)d_ws + needXQ + needW8);
    quant_x_kernel<<<M_TOTAL, 256, 0, stream>>>(x, xq, qrow);
    dequant_w8_kernel<<<1024, 256, 0, stream>>>(wq, w8);
    gemm256_i8_kernel<<<(M_TOTAL / BM) * (N_TOTAL / BN), 512, 0, stream>>>(
        xq, w8, qrow, scales, bias, out);
  } else {
    const size_t total = (size_t)M_TOTAL * N_TOTAL;
    naive_int4_kernel<<<(unsigned)(total / 256), 256, 0, stream>>>(x, wq, scales, bias, out);
  }
}